// Round 14
// baseline (420.583 us; speedup 1.0000x reference)
//
#include <hip/hip_runtime.h>
#include <cstdint>
#include <math.h>

typedef float f32x4 __attribute__((ext_vector_type(4)));
typedef float f32x16 __attribute__((ext_vector_type(16)));
typedef __bf16 bf16x8 __attribute__((ext_vector_type(8)));
typedef unsigned short u16x8 __attribute__((ext_vector_type(8)));
typedef unsigned short u16x4 __attribute__((ext_vector_type(4)));

typedef __attribute__((address_space(1))) const void* gas_cvptr;
typedef __attribute__((address_space(3))) void* las_vptr;

#define WAITV12 asm volatile("s_waitcnt vmcnt(12)" ::: "memory")
#define WAITV8 asm volatile("s_waitcnt vmcnt(8)" ::: "memory")
#define WAITV4 asm volatile("s_waitcnt vmcnt(4)" ::: "memory")
#define WAITV0 asm volatile("s_waitcnt vmcnt(0)" ::: "memory")
#define WAITL0 asm volatile("s_waitcnt lgkmcnt(0)" ::: "memory")
#define SB()   __builtin_amdgcn_sched_barrier(0)
#define BAR()  __builtin_amdgcn_s_barrier()

__device__ __forceinline__ unsigned short f32_to_bf16(float f) {
  uint32_t u = __builtin_bit_cast(uint32_t, f);
  u += 0x7FFFu + ((u >> 16) & 1u);   // round-to-nearest-even
  return (unsigned short)(u >> 16);
}

__device__ __forceinline__ bf16x8 ld_bf16x8(const unsigned short* p) {
  return __builtin_bit_cast(bf16x8, *(const u16x8*)p);
}

// ------- merged conversion kernel: blocks [0,1024) transpose weights, rest convert x -------
__global__ void cvt_all(const float* __restrict__ x, unsigned short* __restrict__ xb, int n4,
                        const float* __restrict__ wq, const float* __restrict__ wk,
                        const float* __restrict__ wv, const float* __restrict__ wo,
                        unsigned short* __restrict__ wqkvT, unsigned short* __restrict__ woT) {
  __shared__ float tile[64][65];
  const int t = threadIdx.x;
  if (blockIdx.x < 1024) {
    const int z = blockIdx.x >> 8;          // 0=wq 1=wk 2=wv 3=wo
    const int rem = blockIdx.x & 255;
    const int by = rem >> 4, bx = rem & 15;
    const float* __restrict__ w = (z == 0) ? wq : (z == 1) ? wk : (z == 2) ? wv : wo;
    unsigned short* __restrict__ out = (z < 3) ? (wqkvT + (size_t)z * 1024 * 1024) : woT;
    const int r0 = by * 64;  // k dim
    const int c0 = bx * 64;  // n dim
#pragma unroll
    for (int i = 0; i < 4; i++) {
      int row = (t >> 4) + i * 16;
      int col = (t & 15) * 4;
      float4 v = *(const float4*)&w[(size_t)(r0 + row) * 1024 + c0 + col];
      tile[row][col] = v.x; tile[row][col + 1] = v.y;
      tile[row][col + 2] = v.z; tile[row][col + 3] = v.w;
    }
    __syncthreads();
#pragma unroll
    for (int i = 0; i < 2; i++) {
      int nr = (t >> 3) + i * 32;
      int kc = (t & 7) * 8;
      u16x8 o;
#pragma unroll
      for (int j = 0; j < 8; j++) o[j] = f32_to_bf16(tile[kc + j][nr]);
      *(u16x8*)&out[(size_t)(c0 + nr) * 1024 + r0 + kc] = o;
    }
  } else {
    const int nb = gridDim.x - 1024;
    const int stride = nb * blockDim.x;
    for (int i = (blockIdx.x - 1024) * blockDim.x + t; i < n4; i += stride) {
      float4 v = ((const float4*)x)[i];
      u16x4 o = { f32_to_bf16(v.x), f32_to_bf16(v.y), f32_to_bf16(v.z), f32_to_bf16(v.w) };
      ((u16x4*)xb)[i] = o;
    }
  }
}

// per-tile fragment set: 12 x bf16x8 = 48 VGPR (4 A-lo, 4 B, 4 A-hi; each frag
// feeds one 32x32x16 MFMA: row/col = lane&31, k = (lane>>5)*8 + j)
struct Frags { bf16x8 afA[4], bfr[4], afB[4]; };

__device__ __forceinline__ void read_frags(Frags& f, const unsigned short* ab,
                                           const unsigned short* bb, int aRow0,
                                           int bRow0, int l31, int kc0, int kc1) {
#pragma unroll
  for (int m = 0; m < 2; m++) {
    const unsigned short* rp = ab + (aRow0 + m * 32 + l31) * 32;
    f.afA[m * 2] = ld_bf16x8(rp + kc0);
    f.afA[m * 2 + 1] = ld_bf16x8(rp + kc1);
  }
#pragma unroll
  for (int n = 0; n < 2; n++) {
    const unsigned short* rp = bb + (bRow0 + n * 32 + l31) * 32;
    f.bfr[n * 2] = ld_bf16x8(rp + kc0);
    f.bfr[n * 2 + 1] = ld_bf16x8(rp + kc1);
  }
#pragma unroll
  for (int m = 0; m < 2; m++) {
    const unsigned short* rp = ab + (aRow0 + 64 + m * 32 + l31) * 32;
    f.afB[m * 2] = ld_bf16x8(rp + kc0);
    f.afB[m * 2 + 1] = ld_bf16x8(rp + kc1);
  }
}

// ============ 256x256-tile deep-pipelined GEMM (r5 schedule, 32x32x16 MFMA) ============
// 512 threads = 8 waves (2 wm x 4 wn); wave tile 128x64 = 4x2 frags of 32x32;
// BK=32, 4 K-tile LDS buffers; cross-tile register rotation; one barrier per tile;
// counted vmcnt(8) keeps 2 K-tiles of global_load_lds in flight; stage depth 4.
// 32x32x16 halves MFMA instruction count (16 vs 32 per wave/K-tile) at higher
// per-inst throughput (m119: 2495 TF vs 2075 for 16x16). Same ds_read count/bytes.
// Conflict-free LDS: chunk lc = ks*2 + (lane>>5), phys = lc ^ ((row>>1)&3) —
// rows 0-7 x chunks tile all 32 banks exactly once (b128 floor).
// C/D layout: col = lane&31, row = (reg&3) + 8*(reg>>2) + 4*(lane>>5).
// NOTE (session finding, r2-r12): eight schedule variants all land at ~900 TF —
// the plain-HIP structure ceiling; schedule rewrites at HIP level are exhausted.
template <int EPI>
__global__ __launch_bounds__(512, 2) void gemm256(
    const unsigned short* __restrict__ A, const unsigned short* __restrict__ Bt,
    const float* __restrict__ b0, const float* __restrict__ b1, const float* __restrict__ b2,
    unsigned short* __restrict__ Qb, unsigned short* __restrict__ Kb, unsigned short* __restrict__ Vb,
    float* __restrict__ Out, int Ncols, int K) {
  __shared__ __align__(16) unsigned short As[4][256][32];
  __shared__ __align__(16) unsigned short Bs[4][256][32];
  const int NT = K >> 5;   // must be even (2-tile unrolled loop)
  const int nb = Ncols >> 8;
  const int nwg = gridDim.x;
  const int cpx = nwg >> 3;
  const int bid = blockIdx.x;
  const int wg = (bid & 7) * cpx + (bid >> 3);
  const int tm = wg / nb, tn = wg % nb;
  const int rowBase = tm << 8, colBase = tn << 8;
  const int t = threadIdx.x;
  const int lane = t & 63;
  const int w = t >> 6;
  const int l31 = lane & 31, l5 = lane >> 5;
  const int wm = w >> 2, wn = w & 3;
  const int aRow0 = wm * 128;
  const int bRow0 = wn * 64;
  // swizzled byte offsets (in bf16 elems) for the two 16B k-chunks of a frag row
  const int xr = (l31 >> 1) & 3;
  const int kc0 = (l5 ^ xr) << 3;          // ks=0: logical chunk l5
  const int kc1 = ((2 + l5) ^ xr) << 3;    // ks=1: logical chunk 2+l5

  const int c0 = t, c1 = t + 512;
  const int r0s = c0 >> 2, r1s = c1 >> 2;
  const int l0s = (c0 & 3) ^ ((r0s >> 1) & 3);
  const int l1s = (c1 & 3) ^ ((r1s >> 1) & 3);
  const unsigned short* gA0 = A + (size_t)(rowBase + r0s) * K + l0s * 8;
  const unsigned short* gA1 = A + (size_t)(rowBase + r1s) * K + l1s * 8;
  const unsigned short* gB0 = Bt + (size_t)(colBase + r0s) * K + l0s * 8;
  const unsigned short* gB1 = Bt + (size_t)(colBase + r1s) * K + l1s * 8;

#define STAGE_AB(tile_) do { int b_ = (tile_) & 3; int kt_ = (tile_) << 5;                    \
    __builtin_amdgcn_global_load_lds((gas_cvptr)(gA0 + kt_),                                  \
        (las_vptr)(&As[b_][0][0] + c0 * 8), 16, 0, 0);                                        \
    __builtin_amdgcn_global_load_lds((gas_cvptr)(gA1 + kt_),                                  \
        (las_vptr)(&As[b_][0][0] + c1 * 8), 16, 0, 0);                                        \
    __builtin_amdgcn_global_load_lds((gas_cvptr)(gB0 + kt_),                                  \
        (las_vptr)(&Bs[b_][0][0] + c0 * 8), 16, 0, 0);                                        \
    __builtin_amdgcn_global_load_lds((gas_cvptr)(gB1 + kt_),                                  \
        (las_vptr)(&Bs[b_][0][0] + c1 * 8), 16, 0, 0); } while (0)

  STAGE_AB(0); STAGE_AB(1); STAGE_AB(2); STAGE_AB(3);
  WAITV12;
  BAR();

  f32x16 acc[4][2] = {};
  Frags F0, F1;
  read_frags(F0, &As[0][0][0], &Bs[0][0][0], aRow0, bRow0, l31, kc0, kc1);

#define TILE_BODY(tt_, CUR, NXT) do {                                                         \
    WAITL0; SB();                                                                             \
    __builtin_amdgcn_s_setprio(1);                                                            \
    _Pragma("unroll")                                                                         \
    for (int m = 0; m < 2; m++)                                                               \
      _Pragma("unroll")                                                                       \
      for (int n = 0; n < 2; n++)                                                             \
        _Pragma("unroll")                                                                     \
        for (int ks = 0; ks < 2; ks++)                                                        \
          acc[m][n] = __builtin_amdgcn_mfma_f32_32x32x16_bf16(CUR.afA[m * 2 + ks],            \
                          CUR.bfr[n * 2 + ks], acc[m][n], 0, 0, 0);                           \
    __builtin_amdgcn_s_setprio(0);                                                            \
    if ((tt_) <= NT - 4)      WAITV8;                                                         \
    else if ((tt_) == NT - 3) WAITV4;                                                         \
    else if ((tt_) == NT - 2) WAITV0;                                                         \
    BAR();                                                                                    \
    if ((tt_) + 1 < NT)                                                                       \
      read_frags(NXT, &As[((tt_) + 1) & 3][0][0], &Bs[((tt_) + 1) & 3][0][0],                 \
                 aRow0, bRow0, l31, kc0, kc1);                                                \
    if ((tt_) + 4 < NT) STAGE_AB((tt_) + 4);                                                  \
    __builtin_amdgcn_s_setprio(1);                                                            \
    _Pragma("unroll")                                                                         \
    for (int m = 0; m < 2; m++)                                                               \
      _Pragma("unroll")                                                                       \
      for (int n = 0; n < 2; n++)                                                             \
        _Pragma("unroll")                                                                     \
        for (int ks = 0; ks < 2; ks++)                                                        \
          acc[2 + m][n] = __builtin_amdgcn_mfma_f32_32x32x16_bf16(CUR.afB[m * 2 + ks],        \
                              CUR.bfr[n * 2 + ks], acc[2 + m][n], 0, 0, 0);                   \
    __builtin_amdgcn_s_setprio(0);                                                            \
  } while (0)

  for (int tt = 0; tt < NT; tt += 2) {
    TILE_BODY(tt, F0, F1);
    TILE_BODY(tt + 1, F1, F0);
  }
#undef TILE_BODY
#undef STAGE_AB

  if (EPI == 0) {
    const int part = colBase >> 10;
    const float* __restrict__ bias = (part == 0) ? b0 : (part == 1) ? b1 : b2;
    unsigned short* __restrict__ dst = (part == 0) ? Qb : (part == 1) ? Kb : Vb;
#pragma unroll
    for (int mi = 0; mi < 4; mi++) {
      const int rowb = rowBase + aRow0 + mi * 32 + 4 * l5;
#pragma unroll
      for (int n = 0; n < 2; n++) {
        const int col = colBase + bRow0 + n * 32 + l31;
        const int within = col & 1023;
        const int h = within >> 6, dh = within & 63;
        const float bi = bias[within];
#pragma unroll
        for (int r = 0; r < 16; r++) {
          const int row = rowb + (r & 3) + 8 * (r >> 2);
          const int b = row >> 6, s = row & 63;
          dst[(size_t)((b * 16 + h) * 64 + s) * 64 + dh] = f32_to_bf16(acc[mi][n][r] + bi);
        }
      }
    }
  } else {
#pragma unroll
    for (int mi = 0; mi < 4; mi++) {
      const int rowb = rowBase + aRow0 + mi * 32 + 4 * l5;
#pragma unroll
      for (int n = 0; n < 2; n++) {
        const int col = colBase + bRow0 + n * 32 + l31;
        const float bi = b0[col];
#pragma unroll
        for (int r = 0; r < 16; r++) {
          const int row = rowb + (r & 3) + 8 * (r >> 2);
          float v = acc[mi][n][r] + bi;
          v = 0.5f * v * (1.0f + erff(v * 0.70710678118654752f));
          Out[(size_t)row * 1024 + col] = v;
        }
      }
    }
  }
}

// -------- attention per (b,h): 64x64, 4 waves, ONE barrier (r13 form) --------
__global__ __launch_bounds__(256) void attn(
    const unsigned short* __restrict__ Qb, const unsigned short* __restrict__ Kb,
    const unsigned short* __restrict__ Vb, unsigned short* __restrict__ ctx) {
  __shared__ __align__(16) unsigned short Ks[64][72];
  __shared__ __align__(16) unsigned short Vt[64][72];   // transposed: [dh][s]
  __shared__ __align__(16) unsigned short Ps[64][72];
  const int bh = blockIdx.x;
  const int b = bh >> 4, h = bh & 15;
  const int t = threadIdx.x, lane = t & 63, w = t >> 6;
  const int li = lane & 15, lg = lane >> 4;
  const unsigned short* __restrict__ Qg = Qb + (size_t)bh * 4096;
  const unsigned short* __restrict__ Kg = Kb + (size_t)bh * 4096;
  const unsigned short* __restrict__ Vg = Vb + (size_t)bh * 4096;

  bf16x8 qa[2];
#pragma unroll
  for (int ks = 0; ks < 2; ks++)
    qa[ks] = ld_bf16x8(&Qg[(w * 16 + li) * 64 + ks * 32 + lg * 8]);

#pragma unroll
  for (int i = 0; i < 2; i++) {
    const int c = t + i * 256;
    const int row = c >> 3, col8 = (c & 7) * 8;
    *(u16x8*)&Ks[row][col8] = *(const u16x8*)&Kg[row * 64 + col8];
    u16x8 v = *(const u16x8*)&Vg[row * 64 + col8];
#pragma unroll
    for (int j = 0; j < 8; j++) Vt[col8 + j][row] = v[j];
  }
  __syncthreads();

  f32x4 sc[4] = {};
#pragma unroll
  for (int ks = 0; ks < 2; ks++) {
#pragma unroll
    for (int n = 0; n < 4; n++) {
      bf16x8 kf = ld_bf16x8(&Ks[n * 16 + li][ks * 32 + lg * 8]);
      sc[n] = __builtin_amdgcn_mfma_f32_16x16x32_bf16(qa[ks], kf, sc[n], 0, 0, 0);
    }
  }

#pragma unroll
  for (int r = 0; r < 4; r++) {
    float v0 = sc[0][r] * 0.03125f, v1 = sc[1][r] * 0.03125f;
    float v2 = sc[2][r] * 0.03125f, v3 = sc[3][r] * 0.03125f;
    float mx = fmaxf(fmaxf(v0, v1), fmaxf(v2, v3));
#pragma unroll
    for (int off = 1; off < 16; off <<= 1) mx = fmaxf(mx, __shfl_xor(mx, off, 64));
    float e0 = __expf(v0 - mx), e1 = __expf(v1 - mx);
    float e2 = __expf(v2 - mx), e3 = __expf(v3 - mx);
    float sum = e0 + e1 + e2 + e3;
#pragma unroll
    for (int off = 1; off < 16; off <<= 1) sum += __shfl_xor(sum, off, 64);
    float is = 1.0f / sum;
    const int q = w * 16 + lg * 4 + r;
    Ps[q][0 * 16 + li] = f32_to_bf16(e0 * is);
    Ps[q][1 * 16 + li] = f32_to_bf16(e1 * is);
    Ps[q][2 * 16 + li] = f32_to_bf16(e2 * is);
    Ps[q][3 * 16 + li] = f32_to_bf16(e3 * is);
  }
  // no barrier: Ps rows are wave-private (write rows 16w..16w+15, read the same)

  f32x4 oc[4] = {};
#pragma unroll
  for (int ks = 0; ks < 2; ks++) {
    bf16x8 pa = ld_bf16x8(&Ps[w * 16 + li][ks * 32 + lg * 8]);
#pragma unroll
    for (int n = 0; n < 4; n++) {
      bf16x8 vf = ld_bf16x8(&Vt[n * 16 + li][ks * 32 + lg * 8]);
      oc[n] = __builtin_amdgcn_mfma_f32_16x16x32_bf16(pa, vf, oc[n], 0, 0, 0);
    }
  }
#pragma unroll
  for (int n = 0; n < 4; n++)
#pragma unroll
    for (int r = 0; r < 4; r++)
      ctx[(size_t)(b * 64 + w * 16 + lg * 4 + r) * 1024 + h * 64 + n * 16 + li] =
          f32_to_bf16(oc[n][r]);
}

extern "C" void kernel_launch(void* const* d_in, const int* in_sizes, int n_in,
                              void* d_out, int out_size, void* d_ws, size_t ws_size,
                              hipStream_t stream) {
  const float* x  = (const float*)d_in[0];
  const float* wq = (const float*)d_in[1];
  const float* bq = (const float*)d_in[2];
  const float* wk = (const float*)d_in[3];
  const float* bk = (const float*)d_in[4];
  const float* wv = (const float*)d_in[5];
  const float* bv = (const float*)d_in[6];
  const float* wo = (const float*)d_in[7];
  const float* bo = (const float*)d_in[8];
  float* out = (float*)d_out;

  const int D = 1024;
  const int M = in_sizes[0] / D;  // B*S = 32768

  char* ws = (char*)d_ws;
  unsigned short* xb    = (unsigned short*)ws;
  unsigned short* wqkvT = (unsigned short*)(ws + (size_t)M * 1024 * 2);
  unsigned short* woT   = wqkvT + (size_t)3 * 1024 * 1024;
  unsigned short* Qb    = woT + (size_t)1024 * 1024;
  unsigned short* Kb    = Qb + (size_t)M * 1024;
  unsigned short* Vb    = Kb + (size_t)M * 1024;
  unsigned short* ctx   = xb;  // reuse: x no longer needed after QKV GEMM

  cvt_all<<<1024 + 2048, 256, 0, stream>>>(x, xb, M * D / 4, wq, wk, wv, wo, wqkvT, woT);
  gemm256<0><<<(M / 256) * (3072 / 256), 512, 0, stream>>>(
      xb, wqkvT, bq, bk, bv, Qb, Kb, Vb, nullptr, 3072, 1024);
  attn<<<(M / 64) * 16, 256, 0, stream>>>(Qb, Kb, Vb, ctx);
  gemm256<1><<<(M / 256) * (1024 / 256), 512, 0, stream>>>(
      ctx, woT, bo, nullptr, nullptr, nullptr, nullptr, nullptr, out, 1024, 1024);
}

// Round 15
// 403.462 us; speedup vs baseline: 1.0424x; 1.0424x over previous
//
#include <hip/hip_runtime.h>
#include <cstdint>
#include <math.h>

typedef float f32x4 __attribute__((ext_vector_type(4)));
typedef __bf16 bf16x8 __attribute__((ext_vector_type(8)));
typedef unsigned short u16x8 __attribute__((ext_vector_type(8)));
typedef unsigned short u16x4 __attribute__((ext_vector_type(4)));

typedef __attribute__((address_space(1))) const void* gas_cvptr;
typedef __attribute__((address_space(3))) void* las_vptr;

#define WAITV12 asm volatile("s_waitcnt vmcnt(12)" ::: "memory")
#define WAITV8 asm volatile("s_waitcnt vmcnt(8)" ::: "memory")
#define WAITV4 asm volatile("s_waitcnt vmcnt(4)" ::: "memory")
#define WAITV0 asm volatile("s_waitcnt vmcnt(0)" ::: "memory")
#define WAITL0 asm volatile("s_waitcnt lgkmcnt(0)" ::: "memory")
#define SB()   __builtin_amdgcn_sched_barrier(0)
#define BAR()  __builtin_amdgcn_s_barrier()

__device__ __forceinline__ unsigned short f32_to_bf16(float f) {
  uint32_t u = __builtin_bit_cast(uint32_t, f);
  u += 0x7FFFu + ((u >> 16) & 1u);   // round-to-nearest-even
  return (unsigned short)(u >> 16);
}

__device__ __forceinline__ bf16x8 ld_bf16x8(const unsigned short* p) {
  return __builtin_bit_cast(bf16x8, *(const u16x8*)p);
}

// ------- merged conversion kernel: blocks [0,1024) transpose weights, rest convert x -------
__global__ void cvt_all(const float* __restrict__ x, unsigned short* __restrict__ xb, int n4,
                        const float* __restrict__ wq, const float* __restrict__ wk,
                        const float* __restrict__ wv, const float* __restrict__ wo,
                        unsigned short* __restrict__ wqkvT, unsigned short* __restrict__ woT) {
  __shared__ float tile[64][65];
  const int t = threadIdx.x;
  if (blockIdx.x < 1024) {
    // weight transpose: [K][N] f32 -> [N][K] bf16 for one 64x64 tile
    const int z = blockIdx.x >> 8;          // 0=wq 1=wk 2=wv 3=wo
    const int rem = blockIdx.x & 255;
    const int by = rem >> 4, bx = rem & 15;
    const float* __restrict__ w = (z == 0) ? wq : (z == 1) ? wk : (z == 2) ? wv : wo;
    unsigned short* __restrict__ out = (z < 3) ? (wqkvT + (size_t)z * 1024 * 1024) : woT;
    const int r0 = by * 64;  // k dim
    const int c0 = bx * 64;  // n dim
#pragma unroll
    for (int i = 0; i < 4; i++) {
      int row = (t >> 4) + i * 16;
      int col = (t & 15) * 4;
      float4 v = *(const float4*)&w[(size_t)(r0 + row) * 1024 + c0 + col];
      tile[row][col] = v.x; tile[row][col + 1] = v.y;
      tile[row][col + 2] = v.z; tile[row][col + 3] = v.w;
    }
    __syncthreads();
#pragma unroll
    for (int i = 0; i < 2; i++) {
      int nr = (t >> 3) + i * 32;
      int kc = (t & 7) * 8;
      u16x8 o;
#pragma unroll
      for (int j = 0; j < 8; j++) o[j] = f32_to_bf16(tile[kc + j][nr]);
      *(u16x8*)&out[(size_t)(c0 + nr) * 1024 + r0 + kc] = o;
    }
  } else {
    // x: f32 -> bf16, grid-stride over float4 chunks
    const int nb = gridDim.x - 1024;
    const int stride = nb * blockDim.x;
    for (int i = (blockIdx.x - 1024) * blockDim.x + t; i < n4; i += stride) {
      float4 v = ((const float4*)x)[i];
      u16x4 o = { f32_to_bf16(v.x), f32_to_bf16(v.y), f32_to_bf16(v.z), f32_to_bf16(v.w) };
      ((u16x4*)xb)[i] = o;
    }
  }
}

// per-tile fragment set: 12 x bf16x8 = 48 VGPR
struct Frags { bf16x8 afA[4], bfr[4], afB[4]; };

__device__ __forceinline__ void read_frags(Frags& f, const unsigned short* ab,
                                           const unsigned short* bb, int aRow0,
                                           int bRow0, int li, int koff) {
#pragma unroll
  for (int m = 0; m < 4; m++) f.afA[m] = ld_bf16x8(ab + (aRow0 + m * 16 + li) * 32 + koff);
#pragma unroll
  for (int n = 0; n < 4; n++) f.bfr[n] = ld_bf16x8(bb + (bRow0 + n * 16 + li) * 32 + koff);
#pragma unroll
  for (int m = 0; m < 4; m++)
    f.afB[m] = ld_bf16x8(ab + (aRow0 + 64 + m * 16 + li) * 32 + koff);
}

// ============ 256x256-tile deep-pipelined GEMM (round-5 best): C = A @ Bt^T ============
// 512 threads = 8 waves (2 wm x 4 wn); wave tile 128x64; BK=32, 4 K-tile LDS buffers.
// Cross-tile register rotation; one barrier per tile; counted vmcnt(8) keeps 2 K-tiles
// of global_load_lds in flight; stage depth 4. Conflict-free LDS via chunk-XOR swizzle.
// NOTE (session finding, r2-r14): nine structural variants (phase splits, occupancy,
// deep staging, 32x32 MFMA shape) all land at ~900 TF — the plain-HIP 2-phase structure
// ceiling. The 32x32x16 shape re-introduces 4-way bank conflicts (row bits >=3 never
// reach the bank index at 64B row stride). Do not re-attempt at HIP level.
template <int EPI>
__global__ __launch_bounds__(512, 2) void gemm256(
    const unsigned short* __restrict__ A, const unsigned short* __restrict__ Bt,
    const float* __restrict__ b0, const float* __restrict__ b1, const float* __restrict__ b2,
    unsigned short* __restrict__ Qb, unsigned short* __restrict__ Kb, unsigned short* __restrict__ Vb,
    float* __restrict__ Out, int Ncols, int K) {
  __shared__ __align__(16) unsigned short As[4][256][32];
  __shared__ __align__(16) unsigned short Bs[4][256][32];
  const int NT = K >> 5;   // must be even (2-tile unrolled loop)
  const int nb = Ncols >> 8;
  const int nwg = gridDim.x;
  const int cpx = nwg >> 3;
  const int bid = blockIdx.x;
  const int wg = (bid & 7) * cpx + (bid >> 3);
  const int tm = wg / nb, tn = wg % nb;
  const int rowBase = tm << 8, colBase = tn << 8;
  const int t = threadIdx.x;
  const int lane = t & 63;
  const int w = t >> 6;
  const int li = lane & 15, lg = lane >> 4;
  const int wm = w >> 2, wn = w & 3;
  const int aRow0 = wm * 128;
  const int bRow0 = wn * 64;
  const int koff = ((lg ^ ((li >> 1) & 3)) << 3);

  const int c0 = t, c1 = t + 512;
  const int r0s = c0 >> 2, r1s = c1 >> 2;
  const int l0s = (c0 & 3) ^ ((r0s >> 1) & 3);
  const int l1s = (c1 & 3) ^ ((r1s >> 1) & 3);
  const unsigned short* gA0 = A + (size_t)(rowBase + r0s) * K + l0s * 8;
  const unsigned short* gA1 = A + (size_t)(rowBase + r1s) * K + l1s * 8;
  const unsigned short* gB0 = Bt + (size_t)(colBase + r0s) * K + l0s * 8;
  const unsigned short* gB1 = Bt + (size_t)(colBase + r1s) * K + l1s * 8;

#define STAGE_AB(tile_) do { int b_ = (tile_) & 3; int kt_ = (tile_) << 5;                    \
    __builtin_amdgcn_global_load_lds((gas_cvptr)(gA0 + kt_),                                  \
        (las_vptr)(&As[b_][0][0] + c0 * 8), 16, 0, 0);                                        \
    __builtin_amdgcn_global_load_lds((gas_cvptr)(gA1 + kt_),                                  \
        (las_vptr)(&As[b_][0][0] + c1 * 8), 16, 0, 0);                                        \
    __builtin_amdgcn_global_load_lds((gas_cvptr)(gB0 + kt_),                                  \
        (las_vptr)(&Bs[b_][0][0] + c0 * 8), 16, 0, 0);                                        \
    __builtin_amdgcn_global_load_lds((gas_cvptr)(gB1 + kt_),                                  \
        (las_vptr)(&Bs[b_][0][0] + c1 * 8), 16, 0, 0); } while (0)

  STAGE_AB(0); STAGE_AB(1); STAGE_AB(2); STAGE_AB(3);
  WAITV12;
  BAR();

  f32x4 acc[8][4] = {};
  Frags F0, F1;
  read_frags(F0, &As[0][0][0], &Bs[0][0][0], aRow0, bRow0, li, koff);

#define TILE_BODY(tt_, CUR, NXT) do {                                                         \
    WAITL0; SB();                                                                             \
    __builtin_amdgcn_s_setprio(1);                                                            \
    _Pragma("unroll")                                                                         \
    for (int m = 0; m < 4; m++)                                                               \
      _Pragma("unroll")                                                                       \
      for (int n = 0; n < 4; n++)                                                             \
        acc[m][n] = __builtin_amdgcn_mfma_f32_16x16x32_bf16(CUR.afA[m], CUR.bfr[n],           \
                                                            acc[m][n], 0, 0, 0);              \
    __builtin_amdgcn_s_setprio(0);                                                            \
    if ((tt_) <= NT - 4)      WAITV8;                                                         \
    else if ((tt_) == NT - 3) WAITV4;                                                         \
    else if ((tt_) == NT - 2) WAITV0;                                                         \
    BAR();                                                                                    \
    if ((tt_) + 1 < NT)                                                                       \
      read_frags(NXT, &As[((tt_) + 1) & 3][0][0], &Bs[((tt_) + 1) & 3][0][0],                 \
                 aRow0, bRow0, li, koff);                                                     \
    if ((tt_) + 4 < NT) STAGE_AB((tt_) + 4);                                                  \
    __builtin_amdgcn_s_setprio(1);                                                            \
    _Pragma("unroll")                                                                         \
    for (int m = 0; m < 4; m++)                                                               \
      _Pragma("unroll")                                                                       \
      for (int n = 0; n < 4; n++)                                                             \
        acc[4 + m][n] = __builtin_amdgcn_mfma_f32_16x16x32_bf16(CUR.afB[m], CUR.bfr[n],       \
                                                                acc[4 + m][n], 0, 0, 0);      \
    __builtin_amdgcn_s_setprio(0);                                                            \
  } while (0)

  for (int tt = 0; tt < NT; tt += 2) {
    TILE_BODY(tt, F0, F1);
    TILE_BODY(tt + 1, F1, F0);
  }
#undef TILE_BODY
#undef STAGE_AB

  if (EPI == 0) {
    const int part = colBase >> 10;
    const float* __restrict__ bias = (part == 0) ? b0 : (part == 1) ? b1 : b2;
    unsigned short* __restrict__ dst = (part == 0) ? Qb : (part == 1) ? Kb : Vb;
#pragma unroll
    for (int mi = 0; mi < 8; mi++) {
      const int rowb = rowBase + aRow0 + mi * 16 + lg * 4;
#pragma unroll
      for (int r = 0; r < 4; r++) {
        const int row = rowb + r;
        const int b = row >> 6, s = row & 63;
#pragma unroll
        for (int n = 0; n < 4; n++) {
          const int col = colBase + bRow0 + n * 16 + li;
          const int within = col & 1023;
          const int h = within >> 6, dh = within & 63;
          float v = acc[mi][n][r] + bias[within];
          dst[(size_t)((b * 16 + h) * 64 + s) * 64 + dh] = f32_to_bf16(v);
        }
      }
    }
  } else {
#pragma unroll
    for (int mi = 0; mi < 8; mi++) {
      const int rowb = rowBase + aRow0 + mi * 16 + lg * 4;
#pragma unroll
      for (int r = 0; r < 4; r++) {
#pragma unroll
        for (int n = 0; n < 4; n++) {
          const int col = colBase + bRow0 + n * 16 + li;
          float v = acc[mi][n][r] + b0[col];
          v = 0.5f * v * (1.0f + erff(v * 0.70710678118654752f));
          Out[(size_t)(rowb + r) * 1024 + col] = v;
        }
      }
    }
  }
}

// -------- attention per (b,h): 64x64, 4 waves, ONE barrier --------
// Q fragments direct from global (wave-private rows, no reuse -> staging was
// pure overhead). K + V^T staged in LDS (cross-wave reuse) behind one barrier.
// Ps is wave-private (wave w writes rows 16w..16w+15, reads the same rows) ->
// same-wave LDS RAW is in-order, no second barrier needed.
__global__ __launch_bounds__(256) void attn(
    const unsigned short* __restrict__ Qb, const unsigned short* __restrict__ Kb,
    const unsigned short* __restrict__ Vb, unsigned short* __restrict__ ctx) {
  __shared__ __align__(16) unsigned short Ks[64][72];
  __shared__ __align__(16) unsigned short Vt[64][72];   // transposed: [dh][s]
  __shared__ __align__(16) unsigned short Ps[64][72];
  const int bh = blockIdx.x;
  const int b = bh >> 4, h = bh & 15;
  const int t = threadIdx.x, lane = t & 63, w = t >> 6;
  const int li = lane & 15, lg = lane >> 4;
  const unsigned short* __restrict__ Qg = Qb + (size_t)bh * 4096;
  const unsigned short* __restrict__ Kg = Kb + (size_t)bh * 4096;
  const unsigned short* __restrict__ Vg = Vb + (size_t)bh * 4096;

  // Q fragments for this wave's 16 rows, direct from global
  bf16x8 qa[2];
#pragma unroll
  for (int ks = 0; ks < 2; ks++)
    qa[ks] = ld_bf16x8(&Qg[(w * 16 + li) * 64 + ks * 32 + lg * 8]);

#pragma unroll
  for (int i = 0; i < 2; i++) {
    const int c = t + i * 256;
    const int row = c >> 3, col8 = (c & 7) * 8;
    *(u16x8*)&Ks[row][col8] = *(const u16x8*)&Kg[row * 64 + col8];
    u16x8 v = *(const u16x8*)&Vg[row * 64 + col8];
#pragma unroll
    for (int j = 0; j < 8; j++) Vt[col8 + j][row] = v[j];
  }
  __syncthreads();

  f32x4 sc[4] = {};
#pragma unroll
  for (int ks = 0; ks < 2; ks++) {
#pragma unroll
    for (int n = 0; n < 4; n++) {
      bf16x8 kf = ld_bf16x8(&Ks[n * 16 + li][ks * 32 + lg * 8]);
      sc[n] = __builtin_amdgcn_mfma_f32_16x16x32_bf16(qa[ks], kf, sc[n], 0, 0, 0);
    }
  }

#pragma unroll
  for (int r = 0; r < 4; r++) {
    float v0 = sc[0][r] * 0.03125f, v1 = sc[1][r] * 0.03125f;
    float v2 = sc[2][r] * 0.03125f, v3 = sc[3][r] * 0.03125f;
    float mx = fmaxf(fmaxf(v0, v1), fmaxf(v2, v3));
#pragma unroll
    for (int off = 1; off < 16; off <<= 1) mx = fmaxf(mx, __shfl_xor(mx, off, 64));
    float e0 = __expf(v0 - mx), e1 = __expf(v1 - mx);
    float e2 = __expf(v2 - mx), e3 = __expf(v3 - mx);
    float sum = e0 + e1 + e2 + e3;
#pragma unroll
    for (int off = 1; off < 16; off <<= 1) sum += __shfl_xor(sum, off, 64);
    float is = 1.0f / sum;
    const int q = w * 16 + lg * 4 + r;
    Ps[q][0 * 16 + li] = f32_to_bf16(e0 * is);
    Ps[q][1 * 16 + li] = f32_to_bf16(e1 * is);
    Ps[q][2 * 16 + li] = f32_to_bf16(e2 * is);
    Ps[q][3 * 16 + li] = f32_to_bf16(e3 * is);
  }
  // no barrier: Ps rows are wave-private (write rows 16w..16w+15, read the same)

  f32x4 oc[4] = {};
#pragma unroll
  for (int ks = 0; ks < 2; ks++) {
    bf16x8 pa = ld_bf16x8(&Ps[w * 16 + li][ks * 32 + lg * 8]);
#pragma unroll
    for (int n = 0; n < 4; n++) {
      bf16x8 vf = ld_bf16x8(&Vt[n * 16 + li][ks * 32 + lg * 8]);
      oc[n] = __builtin_amdgcn_mfma_f32_16x16x32_bf16(pa, vf, oc[n], 0, 0, 0);
    }
  }
#pragma unroll
  for (int n = 0; n < 4; n++)
#pragma unroll
    for (int r = 0; r < 4; r++)
      ctx[(size_t)(b * 64 + w * 16 + lg * 4 + r) * 1024 + h * 64 + n * 16 + li] =
          f32_to_bf16(oc[n][r]);
}

extern "C" void kernel_launch(void* const* d_in, const int* in_sizes, int n_in,
                              void* d_out, int out_size, void* d_ws, size_t ws_size,
                              hipStream_t stream) {
  const float* x  = (const float*)d_in[0];
  const float* wq = (const float*)d_in[1];
  const float* bq = (const float*)d_in[2];
  const float* wk = (const float*)d_in[3];
  const float* bk = (const float*)d_in[4];
  const float* wv = (const float*)d_in[5];
  const float* bv = (const float*)d_in[6];
  const float* wo = (const float*)d_in[7];
  const float* bo = (const float*)d_in[8];
  float* out = (float*)d_out;

  const int D = 1024;
  const int M = in_sizes[0] / D;  // B*S = 32768

  char* ws = (char*)d_ws;
  unsigned short* xb    = (unsigned short*)ws;
  unsigned short* wqkvT = (unsigned short*)(ws + (size_t)M * 1024 * 2);
  unsigned short* woT   = wqkvT + (size_t)3 * 1024 * 1024;
  unsigned short* Qb    = woT + (size_t)1024 * 1024;
  unsigned short* Kb    = Qb + (size_t)M * 1024;
  unsigned short* Vb    = Kb + (size_t)M * 1024;
  unsigned short* ctx   = xb;  // reuse: x no longer needed after QKV GEMM

  cvt_all<<<1024 + 2048, 256, 0, stream>>>(x, xb, M * D / 4, wq, wk, wv, wo, wqkvT, woT);
  gemm256<0><<<(M / 256) * (3072 / 256), 512, 0, stream>>>(
      xb, wqkvT, bq, bk, bv, Qb, Kb, Vb, nullptr, 3072, 1024);
  attn<<<(M / 64) * 16, 256, 0, stream>>>(Qb, Kb, Vb, ctx);
  gemm256<1><<<(M / 256) * (1024 / 256), 512, 0, stream>>>(
      ctx, woT, bo, nullptr, nullptr, nullptr, nullptr, nullptr, out, 1024, 1024);
}